// Round 11
// baseline (111.172 us; speedup 1.0000x reference)
//
#include <hip/hip_runtime.h>
#include <hip/hip_bf16.h>

// ---------------------------------------------------------------------------
// Binary CNN forward (eval):
//  conv3x3(sign(x), sign(W1)) + b1 -> maxpool2x2 -> BN -> hardtanh -> sign
//  -> (i8 MFMA GEMM vs sign(W2)) + b2 -> BN -> hardtanh
//  -> fused W3 projection (atomic partial sums) -> +b3, log_softmax
//
// All sign arithmetic is exact integer math (i8 dot products / i32 MFMA).
// mm_i8 (R11): A is stored by stage1 in FRAGMENT-PACKED order:
//   Ap[ ((m>>5)*196 + (k>>5))*1024 + ((k>>4)&1)*512 + (m&31)*16 + (k&15) ]
// so one MFMA A-fragment = one contiguous 1KB global_load_dwordx4
// (lane L reads base + L*16 -> row=L&31, k-half=L>>5: exact operand map).
// A goes global->VGPR directly (parity double-buffer, 2 chunks ahead);
// B keeps the proven swizzled global_load_lds double buffer. This cuts the
// R7/R9/R10-diagnosed LDS-pipe load by ~half while keeping 8 waves/CU.
// ---------------------------------------------------------------------------

#define EPS 1e-5f

typedef int i32x4 __attribute__((ext_vector_type(4)));
typedef int i32x16 __attribute__((ext_vector_type(16)));

#define GLD_LDS(gsrc, ldst)                                                   \
  __builtin_amdgcn_global_load_lds(                                           \
      (const __attribute__((address_space(1))) void*)(gsrc),                  \
      (__attribute__((address_space(3))) void*)(ldst), 16, 0, 0)

// v_dot4_i32_i8: 4-way i8 dot + i32 acc in one instruction
#if defined(__has_builtin)
#if __has_builtin(__builtin_amdgcn_sdot4)
#define SDOT4(a, b, c) __builtin_amdgcn_sdot4((int)(a), (int)(b), (c), false)
#endif
#endif
#ifndef SDOT4
static __device__ __forceinline__ int sdot4_fb(int a, int b, int c) {
#pragma unroll
  for (int k = 0; k < 4; k++)
    c += ((int)(signed char)(a >> (8 * k))) * ((int)(signed char)(b >> (8 * k)));
  return c;
}
#define SDOT4(a, b, c) sdot4_fb((int)(a), (int)(b), (c))
#endif

// ---------- Stage 1 (merged): conv+pool+BN sign -> Ap | sign(W2) -> B8 ------
__global__ __launch_bounds__(256) void stage1(
    const float* __restrict__ x, const float* __restrict__ W1,
    const float* __restrict__ b1, const float* __restrict__ g1,
    const float* __restrict__ be1, const float* __restrict__ m1,
    const float* __restrict__ v1, const float* __restrict__ W2,
    signed char* __restrict__ Ap, signed char* __restrict__ B8) {
  const int t = threadIdx.x;

  if (blockIdx.x >= 4096) {
    // ---- pack sign(W2) rows as int8: float4 loads, char4 stores ----
    const int row = blockIdx.x - 4096;
    const float4* wr4 = (const float4*)(W2 + (long)row * 6272);  // 1568 vec4
    signed char* br = B8 + (long)row * 6272;
#pragma unroll
    for (int it = 0; it < 7; it++) {
      int f4 = it * 256 + t;
      if (f4 < 1568) {
        float4 v = wr4[f4];
        char4 o;
        o.x = (v.x >= 0.f) ? 1 : -1;
        o.y = (v.y >= 0.f) ? 1 : -1;
        o.z = (v.z >= 0.f) ? 1 : -1;
        o.w = (v.w >= 0.f) ? 1 : -1;
        *(char4*)(br + f4 * 4) = o;
      }
    }
    return;
  }

  // ---- conv path ----
  __shared__ signed char sxb[30 * 32];  // padded binarized image, bytes
  __shared__ int wdw[32][3][2];         // weight dwords: [c][kh][dj]
  __shared__ float cAB[32][2];          // {cA, cB} per channel

  const int b = blockIdx.x;
  for (int i = t; i < 240; i += 256) ((int*)sxb)[i] = 0;  // zero incl. border
  __syncthreads();

  const float* xb = x + b * 784;
  for (int p = t; p < 784; p += 256) {
    float v = xb[p];
    sxb[(p / 28 + 1) * 32 + (p % 28) + 1] = (v >= 0.f) ? (signed char)1
                                                       : (signed char)-1;
  }
  if (t < 96) {
    int c = t / 3, kh = t - c * 3;
    const float* wp = W1 + c * 9 + kh * 3;
    unsigned u0 = (wp[0] >= 0.f) ? 0x01u : 0xFFu;
    unsigned u1 = (wp[1] >= 0.f) ? 0x01u : 0xFFu;
    unsigned u2 = (wp[2] >= 0.f) ? 0x01u : 0xFFu;
    wdw[c][kh][0] = (int)((u2 << 16) | (u1 << 8) | u0);   // (w0,w1,w2,0)
    wdw[c][kh][1] = (int)((u2 << 24) | (u1 << 16) | (u0 << 8));  // (0,w0,w1,w2)
  }
  if (t < 32) {
    float sc = g1[t] * rsqrtf(v1[t] + EPS);
    cAB[t][0] = sc;
    cAB[t][1] = sc * (b1[t] - m1[t]) + be1[t];  // pred = cA*maxconv + cB >= 0
  }
  __syncthreads();

  if (t < 196) {
    const int h = t / 14, w = t - h * 14;
    const int i0 = 2 * h, j0 = 2 * w;
    const int base = j0 & ~3, sh = (j0 & 3) * 8;  // sh in {0,16}
    unsigned prow[4];
#pragma unroll
    for (int ii = 0; ii < 4; ii++) {
      const int* rp = (const int*)&sxb[(i0 + ii) * 32 + base];
      unsigned long long chunk =
          (unsigned)rp[0] | ((unsigned long long)(unsigned)rp[1] << 32);
      prow[ii] = (unsigned)(chunk >> sh);  // bytes j0..j0+3 of padded row
    }
    // packed-A write base for this image (m = b)
    const long rgbase = (long)(b >> 5) * 196;
    const int mlow = (b & 31) << 4;
#pragma unroll 8
    for (int c = 0; c < 32; c++) {
      int w00 = wdw[c][0][0], w01 = wdw[c][0][1];
      int w10 = wdw[c][1][0], w11 = wdw[c][1][1];
      int w20 = wdw[c][2][0], w21 = wdw[c][2][1];
      int c00 = SDOT4(prow[0], w00, SDOT4(prow[1], w10, SDOT4(prow[2], w20, 0)));
      int c01 = SDOT4(prow[0], w01, SDOT4(prow[1], w11, SDOT4(prow[2], w21, 0)));
      int c10 = SDOT4(prow[1], w00, SDOT4(prow[2], w10, SDOT4(prow[3], w20, 0)));
      int c11 = SDOT4(prow[1], w01, SDOT4(prow[2], w11, SDOT4(prow[3], w21, 0)));
      int mx = max(max(c00, c01), max(c10, c11));
      float pred = cAB[c][0] * (float)mx + cAB[c][1];
      int k = c * 196 + t;
      long off = ((rgbase + (k >> 5)) << 10) + (((k >> 4) & 1) << 9) + mlow +
                 (k & 15);
      Ap[off] = (pred >= 0.f) ? (signed char)1 : (signed char)-1;
    }
  }
}

// ---------- i8 MFMA GEMM 4096x2048 (K=6272) + BN2 + clip + W3 partials ------
#define TM 128
#define TN 128
#define BKB 128   // K bytes per chunk
#define NKC 49    // 6272 / 128

// LDS map:
//  [0,16384)     : B buffer 0 (128 rows x 128 B)
//  [16384,32768) : B buffer 1
//  [0,34816)     : epilogue overlay zb[128][136] bf16 (after main loop)
//  [34816,40096) : w3s[10][132] f32
__global__ __launch_bounds__(256) void mm_i8(
    const signed char* __restrict__ Ap, const signed char* __restrict__ B8,
    const float* __restrict__ b2, const float* __restrict__ g2,
    const float* __restrict__ be2, const float* __restrict__ m2,
    const float* __restrict__ v2, const float* __restrict__ W3,
    float* __restrict__ logits) {
  __shared__ __align__(16) char smem[40096];
  float* w3s = (float*)(smem + 34816);

  const int t = threadIdx.x;
  const int lane = t & 63, wv = t >> 6;
  const int l31 = lane & 31, lh = lane >> 5;
  const int wr = wv >> 1, wc = wv & 1;   // 2x2 wave grid, 64x64 wave tile

  // XCD-aware block swizzle: 512 blocks, 8 XCDs -> each XCD gets 64
  // consecutive swz = 4 M-panels x 16 N-panels (A slice 3.2MB < 4MB L2).
  const int bid = blockIdx.x;
  const int swz = (bid & 7) * 64 + (bid >> 3);
  const long tileM = (long)(swz >> 4) * TM;
  const long tileN = (long)(swz & 15) * TN;

  for (int i = t; i < 1320; i += 256) {
    int cls = i / 132, c = i - cls * 132;
    w3s[i] = (c < 128) ? W3[cls * 2048 + tileN + c] : 0.f;
  }

  // Stage B chunk kc into LDS buffer kc&1: 4 gld_lds per wave.
  // LDS linear (r, sl): off = r*128 + sl*16 holds global slot sl^(r&7);
  // frag read applies the same XOR (proven R6 path, absmax 0.0).
  auto stageB = [&](int kc) {
    const int kb = kc * BKB;
    char* base = smem + (kc & 1) * 16384;
#pragma unroll
    for (int i = 0; i < 4; i++) {
      int seg = wv * 4 + i;
      int o = seg * 1024 + lane * 16;
      int r = o >> 7, sl = (o >> 4) & 7;
      GLD_LDS(B8 + (tileN + r) * 6272 + kb + ((sl ^ (r & 7)) << 4),
              base + seg * 1024);
    }
  };

  // Load this wave's 8 A-fragments for chunk kc straight from packed global:
  // fragment (mt, ks) = 1KB at Ap[((tileM>>5)+wr*2+mt)*196 + kc*4+ks][lane*16].
  const signed char* aBase0 =
      Ap + ((long)((tileM >> 5) + wr * 2) * 196) * 1024 + lane * 16;
  const signed char* aBase1 = aBase0 + 196 * 1024;
  auto loadA = [&](i32x4 (&a)[8], int kc) {
    const long kb = (long)kc * 4096;
#pragma unroll
    for (int ks = 0; ks < 4; ks++) {
      a[ks] = *(const i32x4*)(aBase0 + kb + ks * 1024);
      a[4 + ks] = *(const i32x4*)(aBase1 + kb + ks * 1024);
    }
  };

  i32x16 acc[2][2];
#pragma unroll
  for (int a = 0; a < 2; a++)
#pragma unroll
    for (int q = 0; q < 2; q++) acc[a][q] = (i32x16)0;

  i32x4 aE[8], aO[8];
  stageB(0);
  __builtin_amdgcn_sched_barrier(0);
  loadA(aE, 0);
  loadA(aO, 1);
  __builtin_amdgcn_sched_barrier(0);
  // newest 16 outstanding = aE+aO; waits stageB(0) DMA (+ w3s loads).
  asm volatile("s_waitcnt vmcnt(16)" ::: "memory");
  __builtin_amdgcn_s_barrier();

  // One chunk. Entering: B(kc) ready in LDS, aCur valid (compiler-tracked).
  auto body = [&](int kc, i32x4 (&aCur)[8]) {
    if (kc + 1 < NKC) stageB(kc + 1);
    __builtin_amdgcn_sched_barrier(0);  // pin: stageB issued before A loads
    const char* sBb = smem + (kc & 1) * 16384;
#pragma unroll
    for (int ks = 0; ks < 4; ks++) {
      int slot = ks * 2 + lh;
      i32x4 bf[2];
#pragma unroll
      for (int nt = 0; nt < 2; nt++) {
        int r = wc * 64 + nt * 32 + l31;
        bf[nt] = *(const i32x4*)(sBb + r * 128 + ((slot ^ (r & 7)) << 4));
      }
      __builtin_amdgcn_s_setprio(1);
#pragma unroll
      for (int mt = 0; mt < 2; mt++)
#pragma unroll
        for (int nt = 0; nt < 2; nt++)
          acc[mt][nt] = __builtin_amdgcn_mfma_i32_32x32x32_i8(
              aCur[mt * 4 + ks], bf[nt], acc[mt][nt], 0, 0, 0);
      __builtin_amdgcn_s_setprio(0);
    }
    __builtin_amdgcn_sched_barrier(0);  // pin: A loads after compute
    if (kc + 2 < NKC) loadA(aCur, kc + 2);  // refill consumed parity set
    if (kc + 1 < NKC) {
      if (kc + 2 < NKC)
        asm volatile("s_waitcnt vmcnt(8)" ::: "memory");  // stageB(kc+1) done
      else
        asm volatile("s_waitcnt vmcnt(0)" ::: "memory");
      __builtin_amdgcn_s_barrier();
    }
  };

  for (int kc2 = 0; kc2 + 1 < NKC; kc2 += 2) {  // kc = 0..47
    body(kc2, aE);
    body(kc2 + 1, aO);
  }
  body(NKC - 1, aE);  // kc = 48 (even parity)

  __syncthreads();  // all B reads done; smem may be overlaid

  // ---- epilogue: z = clip(BN2(dot)) as bf16 into LDS, then W3 partials -----
  unsigned short* zb = (unsigned short*)smem;  // [128][136] bf16 = 34816 B
#pragma unroll
  for (int mt = 0; mt < 2; mt++)
#pragma unroll
    for (int nt = 0; nt < 2; nt++) {
      int cl = wc * 64 + nt * 32 + l31;
      int col = (int)tileN + cl;
      float sc = g2[col] * rsqrtf(v2[col] + EPS);
      float off = sc * (b2[col] - m2[col]) + be2[col];
      int rbase = wr * 64 + mt * 32 + 4 * lh;
#pragma unroll
      for (int q = 0; q < 16; q++) {
        int rl = rbase + (q & 3) + 8 * (q >> 2);
        float zz = sc * (float)acc[mt][nt][q] + off;
        zz = fminf(1.f, fmaxf(-1.f, zz));
        __hip_bfloat16 hb = __float2bfloat16(zz);
        zb[rl * 136 + cl] = *(unsigned short*)&hb;
      }
    }
  __syncthreads();

#pragma unroll
  for (int i = 0; i < 5; i++) {
    int task = t + i * 256;           // 1280 tasks = 128 rows x 10 classes
    int row = task / 10, cls = task - row * 10;
    float s = 0.f;
#pragma unroll
    for (int c8 = 0; c8 < 16; c8++) {
      uint4 zB = *(const uint4*)(zb + row * 136 + c8 * 8);  // 8 bf16
      const float* wp = w3s + cls * 132 + c8 * 8;
      float4 w0 = *(const float4*)wp;
      float4 w1 = *(const float4*)(wp + 4);
      s += __uint_as_float(zB.x << 16) * w0.x +
           __uint_as_float(zB.x & 0xffff0000u) * w0.y +
           __uint_as_float(zB.y << 16) * w0.z +
           __uint_as_float(zB.y & 0xffff0000u) * w0.w;
      s += __uint_as_float(zB.z << 16) * w1.x +
           __uint_as_float(zB.z & 0xffff0000u) * w1.y +
           __uint_as_float(zB.w << 16) * w1.z +
           __uint_as_float(zB.w & 0xffff0000u) * w1.w;
    }
    atomicAdd(&logits[(tileM + row) * 10 + cls], s);
  }
}

// ---------- +b3, log_softmax over logits[4096][10] -------------------------
__global__ __launch_bounds__(256) void lsm2(const float* __restrict__ logits,
                                            const float* __restrict__ b3,
                                            float* __restrict__ out) {
  int r = blockIdx.x * 256 + threadIdx.x;
  const float* lr = logits + r * 10;
  float v[10];
#pragma unroll
  for (int j = 0; j < 10; j++) v[j] = lr[j] + b3[j];
  float m = v[0];
#pragma unroll
  for (int j = 1; j < 10; j++) m = fmaxf(m, v[j]);
  float s = 0.f;
#pragma unroll
  for (int j = 0; j < 10; j++) s += expf(v[j] - m);
  float ls = logf(s);
#pragma unroll
  for (int j = 0; j < 10; j++) out[r * 10 + j] = v[j] - m - ls;
}

// ---------------------------------------------------------------------------
extern "C" void kernel_launch(void* const* d_in, const int* in_sizes, int n_in,
                              void* d_out, int out_size, void* d_ws, size_t ws_size,
                              hipStream_t stream) {
  const float* x   = (const float*)d_in[0];
  const float* W1  = (const float*)d_in[1];
  const float* b1  = (const float*)d_in[2];
  const float* g1  = (const float*)d_in[3];
  const float* be1 = (const float*)d_in[4];
  const float* m1  = (const float*)d_in[5];
  const float* v1  = (const float*)d_in[6];
  const float* W2  = (const float*)d_in[7];
  const float* b2  = (const float*)d_in[8];
  const float* g2  = (const float*)d_in[9];
  const float* be2 = (const float*)d_in[10];
  const float* m2  = (const float*)d_in[11];
  const float* v2  = (const float*)d_in[12];
  const float* W3  = (const float*)d_in[13];
  const float* b3  = (const float*)d_in[14];

  char* ws = (char*)d_ws;
  signed char* Ap = (signed char*)ws;                 // 128*196*1024 = 25,690,112 B
  signed char* B8 = (signed char*)(ws + 25690112);    // 2048*6272 = 12,845,056 B
  float* logits = (float*)(ws + 38535168);            // 4096*10*4 = 163,840 B

  hipMemsetAsync(logits, 0, 4096 * 10 * sizeof(float), stream);
  stage1<<<4096 + 2048, 256, 0, stream>>>(x, W1, b1, g1, be1, m1, v1, W2, Ap, B8);
  mm_i8<<<512, 256, 0, stream>>>(Ap, B8, b2, g2, be2, m2, v2, W3, logits);
  lsm2<<<16, 256, 0, stream>>>(logits, b3, (float*)d_out);
}

// Round 12
// 74.221 us; speedup vs baseline: 1.4978x; 1.4978x over previous
//
#include <hip/hip_runtime.h>
#include <hip/hip_bf16.h>

// ---------------------------------------------------------------------------
// Binary CNN forward (eval):
//  conv3x3(sign(x), sign(W1)) + b1 -> maxpool2x2 -> BN -> hardtanh -> sign
//  -> (MX-fp4 MFMA GEMM vs sign(W2)) + b2 -> BN -> hardtanh
//  -> fused W3 projection (atomic partial sums) -> +b3, log_softmax
//
// Signs are packed as fp4 e2m1 nibbles (+1 = 0x2, -1 = 0xA, pad = 0x0).
// mfma_scale_f32_32x32x64_f8f6f4 (fmt 4 = fp4, scale 127 = x1.0) gives the
// exact +-1 dot in f32 (integer partials <= 6272 < 2^24). Rows are padded
// 6272 -> 6400 nibbles (3200 B); pad nibbles are +0.0 and contribute 0.
// mm_fp4 keeps the R6-proven structure (drain-barrier dbuf, swizzled
// global_load_lds, 128x128 tile, 2x2 waves of 64x64): each 128 B LDS row now
// carries K=256, so NKC drops 49 -> 25 at identical per-chunk LDS cost, and
// the MFMA rate doubles (i8 4404 -> fp4 9099 TOPS).
// ---------------------------------------------------------------------------

#define EPS 1e-5f

typedef int i32x4 __attribute__((ext_vector_type(4)));
typedef int i32x8 __attribute__((ext_vector_type(8)));
typedef float f32x16 __attribute__((ext_vector_type(16)));

#define GLD_LDS(gsrc, ldst)                                                   \
  __builtin_amdgcn_global_load_lds(                                           \
      (const __attribute__((address_space(1))) void*)(gsrc),                  \
      (__attribute__((address_space(3))) void*)(ldst), 16, 0, 0)

// v_dot4_i32_i8: 4-way i8 dot + i32 acc in one instruction
#if defined(__has_builtin)
#if __has_builtin(__builtin_amdgcn_sdot4)
#define SDOT4(a, b, c) __builtin_amdgcn_sdot4((int)(a), (int)(b), (c), false)
#endif
#endif
#ifndef SDOT4
static __device__ __forceinline__ int sdot4_fb(int a, int b, int c) {
#pragma unroll
  for (int k = 0; k < 4; k++)
    c += ((int)(signed char)(a >> (8 * k))) * ((int)(signed char)(b >> (8 * k)));
  return c;
}
#define SDOT4(a, b, c) sdot4_fb((int)(a), (int)(b), (c))
#endif

#define RSTRIDE 3200  // bytes per row: 6272 nibbles + 64 B zero pad

// fp4 e2m1 encode of sign: >=0 -> +1.0 (0x2), else -1.0 (0xA)
__device__ __forceinline__ unsigned fp4s(float v) {
  return (v >= 0.f) ? 0x2u : 0xAu;
}

// ---------- Stage 1 (merged): conv+pool+BN sign -> A4 | sign(W2) -> B4 ------
__global__ __launch_bounds__(256) void stage1(
    const float* __restrict__ x, const float* __restrict__ W1,
    const float* __restrict__ b1, const float* __restrict__ g1,
    const float* __restrict__ be1, const float* __restrict__ m1,
    const float* __restrict__ v1, const float* __restrict__ W2,
    unsigned char* __restrict__ A4, unsigned char* __restrict__ B4) {
  const int t = threadIdx.x;

  if (blockIdx.x >= 4096) {
    // ---- pack sign(W2) rows as fp4 nibbles: 8 floats -> 4 bytes ----
    const int row = blockIdx.x - 4096;
    const float4* wr4 = (const float4*)(W2 + (long)row * 6272);
    unsigned char* br = B4 + (long)row * RSTRIDE;
#pragma unroll
    for (int i = 0; i < 4; i++) {
      int u = t + 256 * i;             // u-th group of 8 k-values
      if (u < 784) {
        float4 a = wr4[2 * u], b = wr4[2 * u + 1];
        unsigned w = (fp4s(a.x)) | (fp4s(a.y) << 4) | (fp4s(a.z) << 8) |
                     (fp4s(a.w) << 12) | (fp4s(b.x) << 16) | (fp4s(b.y) << 20) |
                     (fp4s(b.z) << 24) | (fp4s(b.w) << 28);
        *(unsigned*)(br + 4 * u) = w;
      }
    }
    if (t < 16) *(unsigned*)(br + 3136 + 4 * t) = 0u;  // zero pad tail
    return;
  }

  // ---- conv path ----
  __shared__ signed char sxb[30 * 32];  // padded binarized image, bytes
  __shared__ int wdw[32][3][2];         // weight dwords: [c][kh][dj]
  __shared__ float cAB[32][2];          // {cA, cB} per channel
  __shared__ unsigned char abit[6272];  // sign bit per k (1 = +1)

  const int b = blockIdx.x;
  for (int i = t; i < 240; i += 256) ((int*)sxb)[i] = 0;  // zero incl. border
  __syncthreads();

  const float* xb = x + b * 784;
  for (int p = t; p < 784; p += 256) {
    float v = xb[p];
    sxb[(p / 28 + 1) * 32 + (p % 28) + 1] = (v >= 0.f) ? (signed char)1
                                                       : (signed char)-1;
  }
  if (t < 96) {
    int c = t / 3, kh = t - c * 3;
    const float* wp = W1 + c * 9 + kh * 3;
    unsigned u0 = (wp[0] >= 0.f) ? 0x01u : 0xFFu;
    unsigned u1 = (wp[1] >= 0.f) ? 0x01u : 0xFFu;
    unsigned u2 = (wp[2] >= 0.f) ? 0x01u : 0xFFu;
    wdw[c][kh][0] = (int)((u2 << 16) | (u1 << 8) | u0);   // (w0,w1,w2,0)
    wdw[c][kh][1] = (int)((u2 << 24) | (u1 << 16) | (u0 << 8));  // (0,w0,w1,w2)
  }
  if (t < 32) {
    float sc = g1[t] * rsqrtf(v1[t] + EPS);
    cAB[t][0] = sc;
    cAB[t][1] = sc * (b1[t] - m1[t]) + be1[t];  // pred = cA*maxconv + cB >= 0
  }
  __syncthreads();

  if (t < 196) {
    const int h = t / 14, w = t - h * 14;
    const int i0 = 2 * h, j0 = 2 * w;
    const int base = j0 & ~3, sh = (j0 & 3) * 8;  // sh in {0,16}
    unsigned prow[4];
#pragma unroll
    for (int ii = 0; ii < 4; ii++) {
      const int* rp = (const int*)&sxb[(i0 + ii) * 32 + base];
      unsigned long long chunk =
          (unsigned)rp[0] | ((unsigned long long)(unsigned)rp[1] << 32);
      prow[ii] = (unsigned)(chunk >> sh);  // bytes j0..j0+3 of padded row
    }
#pragma unroll 8
    for (int c = 0; c < 32; c++) {
      int w00 = wdw[c][0][0], w01 = wdw[c][0][1];
      int w10 = wdw[c][1][0], w11 = wdw[c][1][1];
      int w20 = wdw[c][2][0], w21 = wdw[c][2][1];
      int c00 = SDOT4(prow[0], w00, SDOT4(prow[1], w10, SDOT4(prow[2], w20, 0)));
      int c01 = SDOT4(prow[0], w01, SDOT4(prow[1], w11, SDOT4(prow[2], w21, 0)));
      int c10 = SDOT4(prow[1], w00, SDOT4(prow[2], w10, SDOT4(prow[3], w20, 0)));
      int c11 = SDOT4(prow[1], w01, SDOT4(prow[2], w11, SDOT4(prow[3], w21, 0)));
      int mx = max(max(c00, c01), max(c10, c11));
      float pred = cAB[c][0] * (float)mx + cAB[c][1];
      abit[c * 196 + t] = (pred >= 0.f) ? 1 : 0;
    }
  }
  __syncthreads();

  // pack bits -> fp4 nibbles, coalesced bytes
  unsigned char* ar = A4 + (long)b * RSTRIDE;
#pragma unroll
  for (int i = 0; i < 13; i++) {
    int j = t + 256 * i;  // byte index
    if (j < 3200) {
      int k0 = 2 * j, k1 = 2 * j + 1;
      unsigned byte = 0;
      if (k0 < 6272) byte |= (abit[k0] ? 0x2u : 0xAu);
      if (k1 < 6272) byte |= (abit[k1] ? 0x2u : 0xAu) << 4;
      ar[j] = (unsigned char)byte;
    }
  }
}

// ---------- MX-fp4 MFMA GEMM 4096x2048 (K=6400 nib) + BN2 + clip + W3 -------
#define TM 128
#define TN 128
#define BKB 128   // bytes per chunk per row = K 256 nibbles
#define NKC 25    // 3200 / 128

// LDS map:
//  [0,32768)     : buffer 0 (sA 16K | sB 16K)   (tiles: 128 rows x 128 B)
//  [32768,65536) : buffer 1
//  [0,34816)     : epilogue overlay zb[128][136] bf16 (after main loop)
//  [65536,70816) : w3s[10][132] f32
__global__ __launch_bounds__(256, 2) void mm_fp4(
    const unsigned char* __restrict__ A4, const unsigned char* __restrict__ B4,
    const float* __restrict__ b2, const float* __restrict__ g2,
    const float* __restrict__ be2, const float* __restrict__ m2,
    const float* __restrict__ v2, const float* __restrict__ W3,
    float* __restrict__ logits) {
  __shared__ __align__(16) char smem[70816];
  float* w3s = (float*)(smem + 65536);

  const int t = threadIdx.x;
  const int lane = t & 63, wv = t >> 6;
  const int l31 = lane & 31, lh = lane >> 5;
  const int wr = wv >> 1, wc = wv & 1;   // 2x2 wave grid, 64x64 wave tile

  // XCD-aware block swizzle: 512 blocks, 8 XCDs -> each XCD gets 64
  // consecutive swz = 4 M-panels x 16 N-panels.
  const int bid = blockIdx.x;
  const int swz = (bid & 7) * 64 + (bid >> 3);
  const long tileM = (long)(swz >> 4) * TM;
  const long tileN = (long)(swz & 15) * TN;

  for (int i = t; i < 1320; i += 256) {
    int cls = i / 132, c = i - cls * 132;
    w3s[i] = (c < 128) ? W3[cls * 2048 + tileN + c] : 0.f;
  }

  // Stage chunk kc into buffer buf: 8 gld_lds per wave (4 A + 4 B).
  // LDS linear (r, sl): off = r*128 + sl*16, holding global slot sl^(r&7)
  // (inverse-swizzled source; frag read applies the same XOR). Proven R6 path.
  auto stage = [&](int buf, int kc) {
    const int kb = kc * BKB;
    char* base = smem + buf * 32768;
#pragma unroll
    for (int i = 0; i < 4; i++) {
      int seg = wv * 4 + i;            // 16 segments x 1 KB = 16 KB
      int o = seg * 1024 + lane * 16;
      int r = o >> 7, sl = (o >> 4) & 7;
      int goff = kb + ((sl ^ (r & 7)) << 4);
      GLD_LDS(A4 + (tileM + r) * RSTRIDE + goff, base + seg * 1024);
      GLD_LDS(B4 + (tileN + r) * RSTRIDE + goff, base + 16384 + seg * 1024);
    }
  };

  f32x16 acc[2][2];
#pragma unroll
  for (int a = 0; a < 2; a++)
#pragma unroll
    for (int q = 0; q < 2; q++) acc[a][q] = (f32x16)0.f;

  stage(0, 0);
  __syncthreads();   // compiler drains vmcnt before s_barrier

  int cur = 0;
  for (int kc = 0; kc < NKC; kc++) {
    if (kc + 1 < NKC) stage(cur ^ 1, kc + 1);  // prefetch overlaps compute
    const char* sAb = smem + cur * 32768;
    const char* sBb = sAb + 16384;
#pragma unroll
    for (int ks = 0; ks < 4; ks++) {   // 4 K-steps of 64 nibbles
      int slot = ks * 2 + lh;          // lane-half lh takes nibbles 0-31/32-63
      i32x8 af[2], bf[2];
#pragma unroll
      for (int mt = 0; mt < 2; mt++) {
        int r = wr * 64 + mt * 32 + l31;
        i32x4 v = *(const i32x4*)(sAb + r * 128 + ((slot ^ (r & 7)) << 4));
        af[mt] = (i32x8){v[0], v[1], v[2], v[3], 0, 0, 0, 0};
      }
#pragma unroll
      for (int nt = 0; nt < 2; nt++) {
        int r = wc * 64 + nt * 32 + l31;
        i32x4 v = *(const i32x4*)(sBb + r * 128 + ((slot ^ (r & 7)) << 4));
        bf[nt] = (i32x8){v[0], v[1], v[2], v[3], 0, 0, 0, 0};
      }
      __builtin_amdgcn_s_setprio(1);
#pragma unroll
      for (int mt = 0; mt < 2; mt++)
#pragma unroll
        for (int nt = 0; nt < 2; nt++)
          acc[mt][nt] = __builtin_amdgcn_mfma_scale_f32_32x32x64_f8f6f4(
              af[mt], bf[nt], acc[mt][nt],
              4, 4,            // cbsz / blgp: fmt 4 = fp4 (e2m1)
              0, 127,          // opsel_a, scale_a = E8M0 127 -> x1.0
              0, 127);         // opsel_b, scale_b
      __builtin_amdgcn_s_setprio(0);
    }
    __syncthreads();   // drains this wave's DMA (vmcnt) + guards buffer swap
    cur ^= 1;
  }

  // ---- epilogue: z = clip(BN2(dot)) as bf16 into LDS, then W3 partials -----
  unsigned short* zb = (unsigned short*)smem;  // [128][136] bf16 = 34816 B
#pragma unroll
  for (int mt = 0; mt < 2; mt++)
#pragma unroll
    for (int nt = 0; nt < 2; nt++) {
      int cl = wc * 64 + nt * 32 + l31;
      int col = (int)tileN + cl;
      float sc = g2[col] * rsqrtf(v2[col] + EPS);
      float off = sc * (b2[col] - m2[col]) + be2[col];
      int rbase = wr * 64 + mt * 32 + 4 * lh;
#pragma unroll
      for (int q = 0; q < 16; q++) {
        int rl = rbase + (q & 3) + 8 * (q >> 2);
        float zz = sc * acc[mt][nt][q] + off;
        zz = fminf(1.f, fmaxf(-1.f, zz));
        __hip_bfloat16 hb = __float2bfloat16(zz);
        zb[rl * 136 + cl] = *(unsigned short*)&hb;
      }
    }
  __syncthreads();

#pragma unroll
  for (int i = 0; i < 5; i++) {
    int task = t + i * 256;           // 1280 tasks = 128 rows x 10 classes
    int row = task / 10, cls = task - row * 10;
    float s = 0.f;
#pragma unroll
    for (int c8 = 0; c8 < 16; c8++) {
      uint4 zB = *(const uint4*)(zb + row * 136 + c8 * 8);  // 8 bf16
      const float* wp = w3s + cls * 132 + c8 * 8;
      float4 w0 = *(const float4*)wp;
      float4 w1 = *(const float4*)(wp + 4);
      s += __uint_as_float(zB.x << 16) * w0.x +
           __uint_as_float(zB.x & 0xffff0000u) * w0.y +
           __uint_as_float(zB.y << 16) * w0.z +
           __uint_as_float(zB.y & 0xffff0000u) * w0.w;
      s += __uint_as_float(zB.z << 16) * w1.x +
           __uint_as_float(zB.z & 0xffff0000u) * w1.y +
           __uint_as_float(zB.w << 16) * w1.z +
           __uint_as_float(zB.w & 0xffff0000u) * w1.w;
    }
    atomicAdd(&logits[(tileM + row) * 10 + cls], s);
  }
}

// ---------- +b3, log_softmax over logits[4096][10] -------------------------
__global__ __launch_bounds__(256) void lsm2(const float* __restrict__ logits,
                                            const float* __restrict__ b3,
                                            float* __restrict__ out) {
  int r = blockIdx.x * 256 + threadIdx.x;
  const float* lr = logits + r * 10;
  float v[10];
#pragma unroll
  for (int j = 0; j < 10; j++) v[j] = lr[j] + b3[j];
  float m = v[0];
#pragma unroll
  for (int j = 1; j < 10; j++) m = fmaxf(m, v[j]);
  float s = 0.f;
#pragma unroll
  for (int j = 0; j < 10; j++) s += expf(v[j] - m);
  float ls = logf(s);
#pragma unroll
  for (int j = 0; j < 10; j++) out[r * 10 + j] = v[j] - m - ls;
}

// ---------------------------------------------------------------------------
extern "C" void kernel_launch(void* const* d_in, const int* in_sizes, int n_in,
                              void* d_out, int out_size, void* d_ws, size_t ws_size,
                              hipStream_t stream) {
  const float* x   = (const float*)d_in[0];
  const float* W1  = (const float*)d_in[1];
  const float* b1  = (const float*)d_in[2];
  const float* g1  = (const float*)d_in[3];
  const float* be1 = (const float*)d_in[4];
  const float* m1  = (const float*)d_in[5];
  const float* v1  = (const float*)d_in[6];
  const float* W2  = (const float*)d_in[7];
  const float* b2  = (const float*)d_in[8];
  const float* g2  = (const float*)d_in[9];
  const float* be2 = (const float*)d_in[10];
  const float* m2  = (const float*)d_in[11];
  const float* v2  = (const float*)d_in[12];
  const float* W3  = (const float*)d_in[13];
  const float* b3  = (const float*)d_in[14];

  char* ws = (char*)d_ws;
  unsigned char* A4 = (unsigned char*)ws;               // 4096*3200 = 13,107,200 B
  unsigned char* B4 = (unsigned char*)(ws + 13107200);  // 2048*3200 = 6,553,600 B
  float* logits = (float*)(ws + 19660800);              // 4096*10*4 = 163,840 B

  hipMemsetAsync(logits, 0, 4096 * 10 * sizeof(float), stream);
  stage1<<<4096 + 2048, 256, 0, stream>>>(x, W1, b1, g1, be1, m1, v1, W2, A4, B4);
  mm_fp4<<<512, 256, 0, stream>>>(A4, B4, b2, g2, be2, m2, v2, W3, logits);
  lsm2<<<16, 256, 0, stream>>>(logits, b3, (float*)d_out);
}